// Round 13
// baseline (311.233 us; speedup 1.0000x reference)
//
#include <hip/hip_runtime.h>
#include <stdint.h>

// Problem constants (fixed by the reference): P=8192, L=64, H=128.
#define PCNT 8192
#define LROW 64
#define HDIM 128
#define XSTR 136                    // x_lds k-stride (f16), 16B-aligned rows
#define W1STR 136                   // W1^T k-stride (K=128 + 8 pad)
#define W23STR 264                  // W2^T/W3^T k-stride (K=256 + 8 pad)
#define W1_ELEMS (128 * W1STR)      // 17408
#define W23_ELEMS (128 * W23STR)    // 33792

typedef _Float16 f16;
typedef __attribute__((ext_vector_type(8))) _Float16 half8;
typedef __attribute__((ext_vector_type(4))) _Float16 half4v;
typedef __attribute__((ext_vector_type(2))) _Float16 half2v;
typedef __attribute__((ext_vector_type(4))) float f32x4;

#define MFMA16(A, B, C) __builtin_amdgcn_mfma_f32_16x16x32_f16((A), (B), (C), 0, 0, 0)

__device__ __forceinline__ half8 ldh8(const f16* p) {
  return *reinterpret_cast<const half8*>(p);
}

union PkU { uint32_t u; half2v h; };
union U4H8 { uint4 u; half8 h; };

__device__ __forceinline__ uint32_t pk2(float lo, float hi) {
  PkU a;
  a.h[0] = (f16)lo;
  a.h[1] = (f16)hi;
  return a.u;
}

__device__ __forceinline__ uint32_t pkmax(uint32_t a, uint32_t b) {
  uint32_t d;
  asm("v_pk_max_f16 %0, %1, %2" : "=v"(d) : "v"(a), "v"(b));
  return d;
}

// ---------------------------------------------------------------------------
// Prep: ws = 3 transposed fp16 weight buffers (fused-K layout):
//   buf0 @0:                 W1^T  [c][k], k<128 real, stride 136
//   buf1 @W1_ELEMS:          W2^T  [c][k], k<256 real (Wa2|Wb2), stride 264
//   buf2 @W1_ELEMS+W23_ELEMS W3^T  same, stride 264
// ---------------------------------------------------------------------------
__global__ void prep_weights(const float* __restrict__ W1,
                             const float* __restrict__ W2,
                             const float* __restrict__ W3,
                             f16* __restrict__ wt) {
  int idx = blockIdx.x * 256 + threadIdx.x;
  if (idx >= W1_ELEMS + 2 * W23_ELEMS) return;
  float v = 0.0f;
  if (idx < W1_ELEMS) {
    int c = idx / W1STR, k = idx - c * W1STR;
    if (k < 128) v = W1[k * 128 + c];
  } else {
    int rem = idx - W1_ELEMS;
    const float* W = (rem < W23_ELEMS) ? W2 : W3;
    if (rem >= W23_ELEMS) rem -= W23_ELEMS;
    int c = rem / W23STR, k = rem - c * W23STR;
    if (k < 256) v = W[k * 128 + c];
  }
  wt[idx] = (f16)v;
}

// ---------------------------------------------------------------------------
// Fused kernel, ROW-SPLIT transposed-D: 2 polylines per block, wave wv owns
// M-tile wv (16 rows x all 128 cols) of BOTH polylines (accA[8]+accB[8] =
// 64 VGPR). Consequences:
//  - LN stats fully wave-local (in-lane 32-col sum + xor16/32): no stats LDS.
//  - x' rows are wave-owned (written and re-read by the same wave): no
//    barrier for x; staging is also wave-local.
//  - only phi crosses waves: each wave writes a masked row-max PARTIAL
//    (128 f16) to parity-double-buffered LDS; next layer's GEMM combines the
//    4 partials on the fly (4 ds_read_b128 + 12 v_pk_max per kc>=4).
//  => ONE barrier per layer, 3 total (R10 had 7).
// Weight fragments: each wave loads all 8 ctiles (same addrs across waves ->
// L1); one load feeds both polylines. Fused-K (K=256 on layers 1/2).
// LDS 38.9 KB -> 4 blocks/CU; __launch_bounds__(256,4) (~110 VGPR body).
// ---------------------------------------------------------------------------
__global__ __launch_bounds__(256, 4)
void fused_subgraph(const float* __restrict__ hs,
                    const int* __restrict__ lens,
                    const f16* __restrict__ wt,
                    const float* __restrict__ b1, const float* __restrict__ g1, const float* __restrict__ be1,
                    const float* __restrict__ b2, const float* __restrict__ g2, const float* __restrict__ be2,
                    const float* __restrict__ b3, const float* __restrict__ g3, const float* __restrict__ be3,
                    float* __restrict__ out) {
  __shared__ __align__(16) f16 xA[LROW * XSTR];            // 17408 B
  __shared__ __align__(16) f16 xB[LROW * XSTR];            // 17408 B
  __shared__ __align__(16) uint32_t pm_lds[2][2][4][64];   // [parity][poly][wave][128 f16], 4 KB

  const int tid = threadIdx.x;
  const int wv = tid >> 6;         // wave = M-tile index 0..3
  const int l = tid & 63;          // lane
  const int pA = blockIdx.x * 2;
  const int pB = pA + 1;

  int lenA = lens[pA];
  lenA = (lenA < 1) ? 1 : (lenA > LROW ? LROW : lenA);
  const int mtA = (lenA + 15) >> 4;
  int lenB = lens[pB];
  lenB = (lenB < 1) ? 1 : (lenB > LROW ? LROW : lenB);
  const int mtB = (lenB + 15) >> 4;

  const int l15 = l & 15;
  const int lg = l >> 4;               // lane group 0..3
  const int ko = lg * 8;               // k offset within a 32-k tile
  const int myrow = wv * 16 + l15;     // this lane's x-row (D col m = l15)

  // ---- stage own M-tile rows of both polylines (wave-local, no barrier) ----
  {
    const int r0 = wv * 16 + lg * 4;   // 4 lg-rows x 4 iters... r = wv*16 + it*4 + lg
    const float* hpA = hs + (size_t)pA * (LROW * HDIM);
    const float* hpB = hs + (size_t)pB * (LROW * HDIM);
    (void)r0;
#pragma unroll
    for (int it = 0; it < 4; ++it) {
      const int r = wv * 16 + it * 4 + lg;
      const int c = l15 * 8;
      if (wv < mtA) {
        float4 va = *reinterpret_cast<const float4*>(hpA + r * HDIM + c);
        float4 vb = *reinterpret_cast<const float4*>(hpA + r * HDIM + c + 4);
        half8 hv;
        hv[0] = (f16)va.x; hv[1] = (f16)va.y; hv[2] = (f16)va.z; hv[3] = (f16)va.w;
        hv[4] = (f16)vb.x; hv[5] = (f16)vb.y; hv[6] = (f16)vb.z; hv[7] = (f16)vb.w;
        *reinterpret_cast<half8*>(&xA[r * XSTR + c]) = hv;
      }
      if (wv < mtB) {
        float4 va = *reinterpret_cast<const float4*>(hpB + r * HDIM + c);
        float4 vb = *reinterpret_cast<const float4*>(hpB + r * HDIM + c + 4);
        half8 hv;
        hv[0] = (f16)va.x; hv[1] = (f16)va.y; hv[2] = (f16)va.z; hv[3] = (f16)va.w;
        hv[4] = (f16)vb.x; hv[5] = (f16)vb.y; hv[6] = (f16)vb.z; hv[7] = (f16)vb.w;
        *reinterpret_cast<half8*>(&xB[r * XSTR + c]) = hv;
      }
    }
  }
  // no __syncthreads: producer == consumer wave (lgkmcnt ordering)

#pragma unroll
  for (int layer = 0; layer < 3; ++layer) {
    const int par = layer & 1;        // this layer writes pm_lds[par]
    const int rpar = par ^ 1;         // reads previous layer's partials
    const float* gv  = (layer == 0) ? g1  : (layer == 1) ? g2  : g3;
    const float* bev = (layer == 0) ? be1 : (layer == 1) ? be2 : be3;
    const float* bv  = (layer == 0) ? b1  : (layer == 1) ? b2  : b3;
    const f16* wa = (layer == 0) ? wt
                   : (layer == 1) ? (wt + W1_ELEMS)
                                  : (wt + W1_ELEMS + W23_ELEMS);
    const int wstr = (layer == 0) ? W1STR : W23STR;
    const int kcN  = (layer == 0) ? 4 : 8;

    // ---- GEMM: acc[ct] = bias + row-slice of (x~ @ W~)^T, K=128/256 ----
    f32x4 accA[8], accB[8];
#pragma unroll
    for (int ct = 0; ct < 8; ++ct) {
      const float4 bl = *reinterpret_cast<const float4*>(bv + ct * 16 + lg * 4);
      f32x4 s;
      s[0] = bl.x; s[1] = bl.y; s[2] = bl.z; s[3] = bl.w;
      accA[ct] = s;
      accB[ct] = s;
    }
#pragma unroll
    for (int kc = 0; kc < 8; ++kc) {
      if (kc >= kcN) break;
      half8 opA, opB;   // MFMA B-operand for this kc (x frag or phi frag)
      if (kc < 4) {
        if (wv < mtA) opA = ldh8(&xA[myrow * XSTR + kc * 32 + ko]);
        if (wv < mtB) opB = ldh8(&xB[myrow * XSTR + kc * 32 + ko]);
      } else {
        const int kw = (kc - 4) * 16 + lg * 4;  // word index of 8-f16 chunk
        {
          U4H8 a0, a1, a2, a3, m;
          a0.u = *reinterpret_cast<const uint4*>(&pm_lds[rpar][0][0][kw]);
          a1.u = *reinterpret_cast<const uint4*>(&pm_lds[rpar][0][1][kw]);
          a2.u = *reinterpret_cast<const uint4*>(&pm_lds[rpar][0][2][kw]);
          a3.u = *reinterpret_cast<const uint4*>(&pm_lds[rpar][0][3][kw]);
          m.u.x = pkmax(pkmax(a0.u.x, a1.u.x), pkmax(a2.u.x, a3.u.x));
          m.u.y = pkmax(pkmax(a0.u.y, a1.u.y), pkmax(a2.u.y, a3.u.y));
          m.u.z = pkmax(pkmax(a0.u.z, a1.u.z), pkmax(a2.u.z, a3.u.z));
          m.u.w = pkmax(pkmax(a0.u.w, a1.u.w), pkmax(a2.u.w, a3.u.w));
          opA = m.h;
        }
        {
          U4H8 a0, a1, a2, a3, m;
          a0.u = *reinterpret_cast<const uint4*>(&pm_lds[rpar][1][0][kw]);
          a1.u = *reinterpret_cast<const uint4*>(&pm_lds[rpar][1][1][kw]);
          a2.u = *reinterpret_cast<const uint4*>(&pm_lds[rpar][1][2][kw]);
          a3.u = *reinterpret_cast<const uint4*>(&pm_lds[rpar][1][3][kw]);
          m.u.x = pkmax(pkmax(a0.u.x, a1.u.x), pkmax(a2.u.x, a3.u.x));
          m.u.y = pkmax(pkmax(a0.u.y, a1.u.y), pkmax(a2.u.y, a3.u.y));
          m.u.z = pkmax(pkmax(a0.u.z, a1.u.z), pkmax(a2.u.z, a3.u.z));
          m.u.w = pkmax(pkmax(a0.u.w, a1.u.w), pkmax(a2.u.w, a3.u.w));
          opB = m.h;
        }
      }
#pragma unroll
      for (int ct = 0; ct < 8; ++ct) {
        half8 wf = ldh8(&wa[(ct * 16 + l15) * wstr + kc * 32 + ko]);
        if (wv < mtA) accA[ct] = MFMA16(wf, opA, accA[ct]);
        if (wv < mtB) accB[ct] = MFMA16(wf, opB, accB[ct]);
      }
    }

    // ---- per-polyline: wave-local LN stats, epilogue, masked row-max ----
#pragma unroll
    for (int poly = 0; poly < 2; ++poly) {
      const int mtP = poly ? mtB : mtA;
      const int lenP = poly ? lenB : lenA;
      f16* xP = poly ? xB : xA;
      f32x4* acc = poly ? accB : accA;
      uint32_t pm[8][2];
#pragma unroll
      for (int ct = 0; ct < 8; ++ct) { pm[ct][0] = 0u; pm[ct][1] = 0u; }

      if (wv < mtP) {
        float s = 0.0f, q = 0.0f;
#pragma unroll
        for (int ct = 0; ct < 8; ++ct) {
          const f32x4 a = acc[ct];
          s += (a[0] + a[1]) + (a[2] + a[3]);
          q = fmaf(a[0], a[0], q);
          q = fmaf(a[1], a[1], q);
          q = fmaf(a[2], a[2], q);
          q = fmaf(a[3], a[3], q);
        }
        s += __shfl_xor(s, 16); q += __shfl_xor(q, 16);
        s += __shfl_xor(s, 32); q += __shfl_xor(q, 32);
        const float mu = s * (1.0f / 128.0f);
        const float var = q * (1.0f / 128.0f) - mu * mu;
        const float rs = rsqrtf(var + 1e-5f);
        const bool valid = myrow < lenP;
#pragma unroll
        for (int ct = 0; ct < 8; ++ct) {
          const float4 gg = *reinterpret_cast<const float4*>(gv + ct * 16 + lg * 4);
          const float4 eb = *reinterpret_cast<const float4*>(bev + ct * 16 + lg * 4);
          float v0 = fmaxf((acc[ct][0] - mu) * rs * gg.x + eb.x, 0.0f);
          float v1 = fmaxf((acc[ct][1] - mu) * rs * gg.y + eb.y, 0.0f);
          float v2 = fmaxf((acc[ct][2] - mu) * rs * gg.z + eb.z, 0.0f);
          float v3 = fmaxf((acc[ct][3] - mu) * rs * gg.w + eb.w, 0.0f);
          if (layer < 2) {  // x' rows are wave-owned: no barrier needed
            half4v h;
            h[0] = (f16)v0; h[1] = (f16)v1; h[2] = (f16)v2; h[3] = (f16)v3;
            *reinterpret_cast<half4v*>(&xP[myrow * XSTR + ct * 16 + lg * 4]) = h;
          }
          pm[ct][0] = pk2(valid ? v0 : 0.0f, valid ? v1 : 0.0f);
          pm[ct][1] = pk2(valid ? v2 : 0.0f, valid ? v3 : 0.0f);
        }
        // max over the 16 rows of this tile (l15 lanes)
#pragma unroll
        for (int d = 1; d <= 8; d <<= 1) {
#pragma unroll
          for (int ct = 0; ct < 8; ++ct) {
            pm[ct][0] = pkmax(pm[ct][0], (uint32_t)__shfl_xor((int)pm[ct][0], d));
            pm[ct][1] = pkmax(pm[ct][1], (uint32_t)__shfl_xor((int)pm[ct][1], d));
          }
        }
      }
      // write this wave's partial (zeros if tile inactive; relu => 0 neutral)
      if (l15 == 0) {
#pragma unroll
        for (int ct = 0; ct < 8; ++ct)
          *reinterpret_cast<uint2*>(&pm_lds[par][poly][wv][ct * 8 + lg * 2]) =
              make_uint2(pm[ct][0], pm[ct][1]);
      }
    }
    __syncthreads();  // partials visible (next layer combines on read)
  }

  // ---- final: combine 4 partials (layer2 wrote parity 0), write output ----
  if (l15 == 0) {
#pragma unroll
    for (int poly = 0; poly < 2; ++poly) {
      float* op = out + (size_t)(poly ? pB : pA) * 256;
#pragma unroll
      for (int c2 = 0; c2 < 2; ++c2) {
        const int ct = wv * 2 + c2;
        const int widx = ct * 8 + lg * 2;
        uint2 q0 = *reinterpret_cast<const uint2*>(&pm_lds[0][poly][0][widx]);
        uint2 q1 = *reinterpret_cast<const uint2*>(&pm_lds[0][poly][1][widx]);
        uint2 q2 = *reinterpret_cast<const uint2*>(&pm_lds[0][poly][2][widx]);
        uint2 q3 = *reinterpret_cast<const uint2*>(&pm_lds[0][poly][3][widx]);
        uint32_t m0 = pkmax(pkmax(q0.x, q1.x), pkmax(q2.x, q3.x));
        uint32_t m1 = pkmax(pkmax(q0.y, q1.y), pkmax(q2.y, q3.y));
        PkU u0, u1;
        u0.u = m0; u1.u = m1;
        float4 o = make_float4((float)u0.h[0], (float)u0.h[1],
                               (float)u1.h[0], (float)u1.h[1]);
        *reinterpret_cast<float4*>(op + ct * 16 + lg * 4) = o;
        *reinterpret_cast<float4*>(op + 128 + ct * 16 + lg * 4) = o;
      }
    }
  }
}

extern "C" void kernel_launch(void* const* d_in, const int* in_sizes, int n_in,
                              void* d_out, int out_size, void* d_ws, size_t ws_size,
                              hipStream_t stream) {
  const float* hs  = (const float*)d_in[0];
  const int* lens  = (const int*)d_in[1];
  const float* W1  = (const float*)d_in[2];
  const float* b1  = (const float*)d_in[3];
  const float* g1  = (const float*)d_in[4];
  const float* be1 = (const float*)d_in[5];
  const float* W2  = (const float*)d_in[6];
  const float* b2  = (const float*)d_in[7];
  const float* g2  = (const float*)d_in[8];
  const float* be2 = (const float*)d_in[9];
  const float* W3  = (const float*)d_in[10];
  const float* b3  = (const float*)d_in[11];
  const float* g3  = (const float*)d_in[12];
  const float* be3 = (const float*)d_in[13];
  float* out = (float*)d_out;
  f16* wt = (f16*)d_ws;  // needs (17408 + 2*33792)*2 = 169984 B of scratch

  const int prep_total = W1_ELEMS + 2 * W23_ELEMS;
  prep_weights<<<(prep_total + 255) / 256, 256, 0, stream>>>(W1, W2, W3, wt);
  fused_subgraph<<<PCNT / 2, 256, 0, stream>>>(hs, lens, wt,
                                               b1, g1, be1, b2, g2, be2, b3, g3, be3,
                                               out);
}

// Round 15
// 112.104 us; speedup vs baseline: 2.7763x; 2.7763x over previous
//
#include <hip/hip_runtime.h>
#include <stdint.h>

// Problem constants (fixed by the reference): P=8192, L=64, H=128.
#define PCNT 8192
#define LROW 64
#define HDIM 128
#define XSTR 136                    // x_lds k-stride (f16), 16B aligned
#define W1STR 136                   // W1^T k-stride (K=128 + 8 pad)
#define W23STR 264                  // W2^T/W3^T k-stride (K=256 + 8 pad)
#define W1_ELEMS (128 * W1STR)      // 17408
#define W23_ELEMS (128 * W23STR)    // 33792

typedef _Float16 f16;
typedef __attribute__((ext_vector_type(8))) _Float16 half8;
typedef __attribute__((ext_vector_type(2))) __fp16 fp16x2;   // builtin cvt_pkrtz type
typedef __attribute__((ext_vector_type(4))) float f32x4;

#define MFMA16(A, B, C) __builtin_amdgcn_mfma_f32_16x16x32_f16((A), (B), (C), 0, 0, 0)

__device__ __forceinline__ half8 ldh8(const f16* p) {
  return *reinterpret_cast<const half8*>(p);
}

union PkU { uint32_t u; fp16x2 h; };

// f32 pair -> packed f16 (round-toward-zero), 1 instruction
__device__ __forceinline__ uint32_t pkrtz2(float a, float b) {
  PkU r;
  r.h = __builtin_amdgcn_cvt_pkrtz(a, b);
  return r.u;
}

__device__ __forceinline__ uint32_t pkmax(uint32_t a, uint32_t b) {
  uint32_t d;
  asm("v_pk_max_f16 %0, %1, %2" : "=v"(d) : "v"(a), "v"(b));
  return d;
}
__device__ __forceinline__ uint32_t pkadd(uint32_t a, uint32_t b) {
  uint32_t d;
  asm("v_pk_add_f16 %0, %1, %2" : "=v"(d) : "v"(a), "v"(b));
  return d;
}
__device__ __forceinline__ uint32_t pkmul(uint32_t a, uint32_t b) {
  uint32_t d;
  asm("v_pk_mul_f16 %0, %1, %2" : "=v"(d) : "v"(a), "v"(b));
  return d;
}
__device__ __forceinline__ uint32_t pkfma(uint32_t a, uint32_t b, uint32_t c) {
  uint32_t d;
  asm("v_pk_fma_f16 %0, %1, %2, %3" : "=v"(d) : "v"(a), "v"(b), "v"(c));
  return d;
}

// ---------------------------------------------------------------------------
// Prep: ws = 3 transposed fp16 weight buffers (fused-K layout):
//   buf0 @0:                 W1^T  [c][k], k<128 real, stride 136
//   buf1 @W1_ELEMS:          W2^T  [c][k], k<256 real (Wa2|Wb2), stride 264
//   buf2 @W1_ELEMS+W23_ELEMS W3^T  same, stride 264
// ---------------------------------------------------------------------------
__global__ void prep_weights(const float* __restrict__ W1,
                             const float* __restrict__ W2,
                             const float* __restrict__ W3,
                             f16* __restrict__ wt) {
  int idx = blockIdx.x * 256 + threadIdx.x;
  if (idx >= W1_ELEMS + 2 * W23_ELEMS) return;
  float v = 0.0f;
  if (idx < W1_ELEMS) {
    int c = idx / W1STR, k = idx - c * W1STR;
    if (k < 128) v = W1[k * 128 + c];
  } else {
    int rem = idx - W1_ELEMS;
    const float* W = (rem < W23_ELEMS) ? W2 : W3;
    if (rem >= W23_ELEMS) rem -= W23_ELEMS;
    int c = rem / W23STR, k = rem - c * W23STR;
    if (k < 256) v = W[k * 128 + c];
  }
  wt[idx] = (f16)v;
}

// stage one polyline's rows [0,16*mtiles): fp32 -> fp16, b128 LDS writes
__device__ __forceinline__ void stage_x(f16* __restrict__ x_lds,
                                        const float* __restrict__ hp,
                                        int mtiles, int tid) {
  for (int it = 0; it < mtiles; ++it) {
    int e = (it * 256 + tid) * 8;
    int r = e >> 7, c = e & 127;
    float4 va = *reinterpret_cast<const float4*>(hp + e);
    float4 vb = *reinterpret_cast<const float4*>(hp + e + 4);
    half8 hv;
    hv[0] = (f16)va.x; hv[1] = (f16)va.y; hv[2] = (f16)va.z; hv[3] = (f16)va.w;
    hv[4] = (f16)vb.x; hv[5] = (f16)vb.y; hv[6] = (f16)vb.z; hv[7] = (f16)vb.w;
    *reinterpret_cast<half8*>(&x_lds[r * XSTR + c]) = hv;
  }
}

// ---------------------------------------------------------------------------
// Fused kernel (R10 base — the proven regime): transposed-D, TWO polylines
// per block processed CONCURRENTLY (each weight fragment load feeds both
// GEMMs), fused-K (K=256 on layers 1/2, phi fragments uniform -> rank-1
// concat term), bias seeds acc, one stats + one phi/x' barrier per layer.
// R14 deltas vs R10 (codegen-local, no structure change):
//  - epilogue LN-affine+relu in PACKED f16 (cvt_pkrtz + v_pk_*): ~22 vs ~52
//    VALU per M-tile; conversions to f16 were needed anyway for x'/phi.
//  - acc tiles with mt >= mtiles left uninitialized (never read).
// __launch_bounds__(256,4): proven spill-free regime (~100 VGPR).
// ---------------------------------------------------------------------------
__global__ __launch_bounds__(256, 4)
void fused_subgraph(const float* __restrict__ hs,
                    const int* __restrict__ lens,
                    const f16* __restrict__ wt,
                    const float* __restrict__ b1, const float* __restrict__ g1, const float* __restrict__ be1,
                    const float* __restrict__ b2, const float* __restrict__ g2, const float* __restrict__ be2,
                    const float* __restrict__ b3, const float* __restrict__ g3, const float* __restrict__ be3,
                    float* __restrict__ out) {
  __shared__ __align__(16) f16 xA[LROW * XSTR];      // 17408 B
  __shared__ __align__(16) f16 xB[LROW * XSTR];      // 17408 B
  __shared__ __align__(16) float2 stats_s[2][LROW][4];  // [poly][row][wave], 4 KB
  __shared__ __align__(16) f16 phiA[HDIM];
  __shared__ __align__(16) f16 phiB[HDIM];

  const int tid = threadIdx.x;
  const int w = tid >> 6;   // wave 0..3
  const int l = tid & 63;   // lane
  const int pA = blockIdx.x * 2;
  const int pB = pA + 1;

  int lenA = lens[pA];
  lenA = (lenA < 1) ? 1 : (lenA > LROW ? LROW : lenA);
  const int mtA = (lenA + 15) >> 4;
  int lenB = lens[pB];
  lenB = (lenB < 1) ? 1 : (lenB > LROW ? LROW : lenB);
  const int mtB = (lenB + 15) >> 4;

  const int l15 = l & 15;
  const int lg = l >> 4;                    // lane group 0..3
  const int ko = lg * 8;                    // k offset within a 32-k tile
  const int cb0 = w * 32 + lg * 4;          // lane's col base, nt=0
  const int cb1 = cb0 + 16;                 // nt=1

  // ---- stage both polylines ----
  stage_x(xA, hs + (size_t)pA * (LROW * HDIM), mtA, tid);
  stage_x(xB, hs + (size_t)pB * (LROW * HDIM), mtB, tid);
  __syncthreads();

#pragma unroll
  for (int layer = 0; layer < 3; ++layer) {
    const float* gv  = (layer == 0) ? g1  : (layer == 1) ? g2  : g3;
    const float* bev = (layer == 0) ? be1 : (layer == 1) ? be2 : be3;
    const float* bv  = (layer == 0) ? b1  : (layer == 1) ? b2  : b3;
    const f16* wa = (layer == 0) ? wt
                   : (layer == 1) ? (wt + W1_ELEMS)
                                  : (wt + W1_ELEMS + W23_ELEMS);
    const int wstr = (layer == 0) ? W1STR : W23STR;
    const int kcN  = (layer == 0) ? 4 : 8;
    const int wrow0 = (w * 32 + l15) * wstr;
    const int wrow1 = wrow0 + 16 * wstr;

    // ---- GEMM both polylines: acc = bias + (x~ @ W~)^T, K=128/256 ----
    f32x4 aA[4][2], aB[4][2];
    {
      const float4 bl0 = *reinterpret_cast<const float4*>(bv + cb0);
      const float4 bl1 = *reinterpret_cast<const float4*>(bv + cb1);
      f32x4 s0, s1;
      s0[0] = bl0.x; s0[1] = bl0.y; s0[2] = bl0.z; s0[3] = bl0.w;
      s1[0] = bl1.x; s1[1] = bl1.y; s1[2] = bl1.z; s1[3] = bl1.w;
#pragma unroll
      for (int mt = 0; mt < 4; ++mt) {
        if (mt < mtA) { aA[mt][0] = s0; aA[mt][1] = s1; }
        if (mt < mtB) { aB[mt][0] = s0; aB[mt][1] = s1; }
      }
    }
#pragma unroll
    for (int kc = 0; kc < 8; ++kc) {
      if (kc >= kcN) break;
      half8 wa0 = ldh8(&wa[wrow0 + kc * 32 + ko]);   // one load, two polylines
      half8 wa1 = ldh8(&wa[wrow1 + kc * 32 + ko]);
      if (kc < 4) {
#pragma unroll
        for (int mt = 0; mt < 4; ++mt) {
          if (mt < mtA) {
            half8 bx = ldh8(&xA[(mt * 16 + l15) * XSTR + kc * 32 + ko]);
            aA[mt][0] = MFMA16(wa0, bx, aA[mt][0]);
            aA[mt][1] = MFMA16(wa1, bx, aA[mt][1]);
          }
        }
#pragma unroll
        for (int mt = 0; mt < 4; ++mt) {
          if (mt < mtB) {
            half8 bx = ldh8(&xB[(mt * 16 + l15) * XSTR + kc * 32 + ko]);
            aB[mt][0] = MFMA16(wa0, bx, aB[mt][0]);
            aB[mt][1] = MFMA16(wa1, bx, aB[mt][1]);
          }
        }
      } else {
        half8 phfA = ldh8(&phiA[(kc - 4) * 32 + ko]);  // uniform -> row-const
        half8 phfB = ldh8(&phiB[(kc - 4) * 32 + ko]);
#pragma unroll
        for (int mt = 0; mt < 4; ++mt) {
          if (mt < mtA) {
            aA[mt][0] = MFMA16(wa0, phfA, aA[mt][0]);
            aA[mt][1] = MFMA16(wa1, phfA, aA[mt][1]);
          }
        }
#pragma unroll
        for (int mt = 0; mt < 4; ++mt) {
          if (mt < mtB) {
            aB[mt][0] = MFMA16(wa0, phfB, aB[mt][0]);
            aB[mt][1] = MFMA16(wa1, phfB, aB[mt][1]);
          }
        }
      }
    }

    // ---- LN stats both polylines (f32, unchanged) ----
#pragma unroll
    for (int mt = 0; mt < 4; ++mt) {
      if (mt < mtA) {
        const f32x4 a0 = aA[mt][0], a1 = aA[mt][1];
        float s = ((a0[0] + a0[1]) + (a0[2] + a0[3])) + ((a1[0] + a1[1]) + (a1[2] + a1[3]));
        float q = a0[0] * a0[0];
        q = fmaf(a0[1], a0[1], q); q = fmaf(a0[2], a0[2], q); q = fmaf(a0[3], a0[3], q);
        q = fmaf(a1[0], a1[0], q); q = fmaf(a1[1], a1[1], q);
        q = fmaf(a1[2], a1[2], q); q = fmaf(a1[3], a1[3], q);
        s += __shfl_xor(s, 16); q += __shfl_xor(q, 16);
        s += __shfl_xor(s, 32); q += __shfl_xor(q, 32);
        if (l < 16) stats_s[0][mt * 16 + l15][w] = make_float2(s, q);
      }
    }
#pragma unroll
    for (int mt = 0; mt < 4; ++mt) {
      if (mt < mtB) {
        const f32x4 a0 = aB[mt][0], a1 = aB[mt][1];
        float s = ((a0[0] + a0[1]) + (a0[2] + a0[3])) + ((a1[0] + a1[1]) + (a1[2] + a1[3]));
        float q = a0[0] * a0[0];
        q = fmaf(a0[1], a0[1], q); q = fmaf(a0[2], a0[2], q); q = fmaf(a0[3], a0[3], q);
        q = fmaf(a1[0], a1[0], q); q = fmaf(a1[1], a1[1], q);
        q = fmaf(a1[2], a1[2], q); q = fmaf(a1[3], a1[3], q);
        s += __shfl_xor(s, 16); q += __shfl_xor(q, 16);
        s += __shfl_xor(s, 32); q += __shfl_xor(q, 32);
        if (l < 16) stats_s[1][mt * 16 + l15][w] = make_float2(s, q);
      }
    }
    __syncthreads();

    // ---- epilogues, PACKED f16 (shared g/beta packs) ----
    const float4 gg0 = *reinterpret_cast<const float4*>(gv + cb0);
    const float4 gg1 = *reinterpret_cast<const float4*>(gv + cb1);
    const float4 eb0 = *reinterpret_cast<const float4*>(bev + cb0);
    const float4 eb1 = *reinterpret_cast<const float4*>(bev + cb1);
    const uint32_t gp0 = pkrtz2(gg0.x, gg0.y), gp1 = pkrtz2(gg0.z, gg0.w);
    const uint32_t gp2 = pkrtz2(gg1.x, gg1.y), gp3 = pkrtz2(gg1.z, gg1.w);
    const uint32_t bp0 = pkrtz2(eb0.x, eb0.y), bp1 = pkrtz2(eb0.z, eb0.w);
    const uint32_t bp2 = pkrtz2(eb1.x, eb1.y), bp3 = pkrtz2(eb1.z, eb1.w);
    const uint32_t zero = 0u;

#pragma unroll
    for (int poly = 0; poly < 2; ++poly) {
      const int mtP = poly ? mtB : mtA;
      const int lenP = poly ? lenB : lenA;
      f16* xP = poly ? xB : xA;
      f16* phiP = poly ? phiB : phiA;
      uint32_t pm[4] = {0u, 0u, 0u, 0u};
#pragma unroll
      for (int mt = 0; mt < 4; ++mt) {
        if (mt < mtP) {
          const f32x4 a0 = poly ? aB[mt][0] : aA[mt][0];
          const f32x4 a1 = poly ? aB[mt][1] : aA[mt][1];
          const int row = mt * 16 + l15;
          float4 r01 = *reinterpret_cast<const float4*>(&stats_s[poly][row][0]);
          float4 r23 = *reinterpret_cast<const float4*>(&stats_s[poly][row][2]);
          float s = (r01.x + r01.z) + (r23.x + r23.z);
          float q = (r01.y + r01.w) + (r23.y + r23.w);
          float mu = s * (1.0f / 128.0f);
          float var = q * (1.0f / 128.0f) - mu * mu;
          float rs = rsqrtf(var + 1e-5f);
          // packed f16 LN-affine + relu: v = max(((a - mu) * rs) * g + be, 0)
          const uint32_t nmu = pkrtz2(-mu, -mu);
          const uint32_t rsp = pkrtz2(rs, rs);
          uint32_t ap0 = pkrtz2(a0[0], a0[1]), ap1 = pkrtz2(a0[2], a0[3]);
          uint32_t ap2 = pkrtz2(a1[0], a1[1]), ap3 = pkrtz2(a1[2], a1[3]);
          uint32_t v0 = pkmax(pkfma(pkmul(pkadd(ap0, nmu), rsp), gp0, bp0), zero);
          uint32_t v1 = pkmax(pkfma(pkmul(pkadd(ap1, nmu), rsp), gp1, bp1), zero);
          uint32_t v2 = pkmax(pkfma(pkmul(pkadd(ap2, nmu), rsp), gp2, bp2), zero);
          uint32_t v3 = pkmax(pkfma(pkmul(pkadd(ap3, nmu), rsp), gp3, bp3), zero);
          if (layer < 2) {  // x' write (b64 pairs)
            *reinterpret_cast<uint2*>(&xP[row * XSTR + cb0]) = make_uint2(v0, v1);
            *reinterpret_cast<uint2*>(&xP[row * XSTR + cb1]) = make_uint2(v2, v3);
          }
          const bool valid = row < lenP;
          pm[0] = pkmax(pm[0], valid ? v0 : zero);
          pm[1] = pkmax(pm[1], valid ? v1 : zero);
          pm[2] = pkmax(pm[2], valid ? v2 : zero);
          pm[3] = pkmax(pm[3], valid ? v3 : zero);
        }
      }
#pragma unroll
      for (int d = 1; d <= 8; d <<= 1) {
#pragma unroll
        for (int j = 0; j < 4; ++j)
          pm[j] = pkmax(pm[j], (uint32_t)__shfl_xor((int)pm[j], d));
      }

      if (layer < 2) {
        if (l15 == 0) {
          *reinterpret_cast<uint2*>(&phiP[cb0]) = make_uint2(pm[0], pm[1]);
          *reinterpret_cast<uint2*>(&phiP[cb1]) = make_uint2(pm[2], pm[3]);
        }
      } else {
        if (l15 == 0) {  // output = concat(phi3, phi3)
          PkU q0, q1, q2, q3;
          q0.u = pm[0]; q1.u = pm[1]; q2.u = pm[2]; q3.u = pm[3];
          float4 o0 = make_float4((float)q0.h[0], (float)q0.h[1], (float)q1.h[0], (float)q1.h[1]);
          float4 o1 = make_float4((float)q2.h[0], (float)q2.h[1], (float)q3.h[0], (float)q3.h[1]);
          float* op = out + (size_t)(poly ? pB : pA) * 256;
          *reinterpret_cast<float4*>(op + cb0) = o0;
          *reinterpret_cast<float4*>(op + cb1) = o1;
          *reinterpret_cast<float4*>(op + 128 + cb0) = o0;
          *reinterpret_cast<float4*>(op + 128 + cb1) = o1;
        }
      }
    }
    if (layer < 2) __syncthreads();  // x' + phi ready for next layer
  }
}

extern "C" void kernel_launch(void* const* d_in, const int* in_sizes, int n_in,
                              void* d_out, int out_size, void* d_ws, size_t ws_size,
                              hipStream_t stream) {
  const float* hs  = (const float*)d_in[0];
  const int* lens  = (const int*)d_in[1];
  const float* W1  = (const float*)d_in[2];
  const float* b1  = (const float*)d_in[3];
  const float* g1  = (const float*)d_in[4];
  const float* be1 = (const float*)d_in[5];
  const float* W2  = (const float*)d_in[6];
  const float* b2  = (const float*)d_in[7];
  const float* g2  = (const float*)d_in[8];
  const float* be2 = (const float*)d_in[9];
  const float* W3  = (const float*)d_in[10];
  const float* b3  = (const float*)d_in[11];
  const float* g3  = (const float*)d_in[12];
  const float* be3 = (const float*)d_in[13];
  float* out = (float*)d_out;
  f16* wt = (f16*)d_ws;  // needs (17408 + 2*33792)*2 = 169984 B of scratch

  const int prep_total = W1_ELEMS + 2 * W23_ELEMS;
  prep_weights<<<(prep_total + 255) / 256, 256, 0, stream>>>(W1, W2, W3, wt);
  fused_subgraph<<<PCNT / 2, 256, 0, stream>>>(hs, lens, wt,
                                               b1, g1, be1, b2, g2, be2, b3, g3, be3,
                                               out);
}